// Round 1
// baseline (2329.347 us; speedup 1.0000x reference)
//
#include <hip/hip_runtime.h>
#include <hip/hip_bf16.h>
#include <cstdint>

#define DEVINL __device__ __forceinline__

typedef __attribute__((ext_vector_type(8))) short bf16x8;   // 8 bf16 in 4 VGPRs
typedef __attribute__((ext_vector_type(4))) float f32x4;

DEVINL unsigned short f2bf(float f) {            // round-to-nearest-even f32 -> bf16
    unsigned int u = __float_as_uint(f);
    u += 0x7fffu + ((u >> 16) & 1u);
    return (unsigned short)(u >> 16);
}
DEVINL float bf2f(unsigned short h) { return __uint_as_float(((unsigned int)h) << 16); }

// async global->LDS, 16B per lane; LDS dest must be wave-uniform base (+lane*16 implicit)
#define GLL16(gsrc, ldst)                                                           \
    __builtin_amdgcn_global_load_lds(                                               \
        (const __attribute__((address_space(1))) unsigned int*)(gsrc),              \
        (__attribute__((address_space(3))) unsigned int*)(ldst), 16, 0, 0)

// ---------------------------------------------------------------------------
// Kernel 1: segment mean.  grid (512, 3), block 256.  Writes avg as bf16 hi/lo.
// ---------------------------------------------------------------------------
__global__ __launch_bounds__(256) void seg_mean(
    const float* __restrict__ emb, const int* __restrict__ wids,
    unsigned short* __restrict__ Ahi, unsigned short* __restrict__ Alo)
{
    __shared__ float seg[64][256];
    __shared__ int cnt[64];
    __shared__ int ids[128];
    const int tid = threadIdx.x;
    const int b   = blockIdx.x;
    const int d0  = blockIdx.y * 256;

    if (tid < 64) cnt[tid] = 0;
    for (int s = 0; s < 64; ++s) seg[s][tid] = 0.0f;
    __syncthreads();
    if (tid < 128) { int s = wids[b * 128 + tid]; ids[tid] = s; atomicAdd(&cnt[s], 1); }
    __syncthreads();

    const float* ep = emb + (size_t)b * 128 * 768 + d0 + tid;
    for (int t = 0; t < 128; t += 4) {
        float v0 = ep[(size_t)(t + 0) * 768];
        float v1 = ep[(size_t)(t + 1) * 768];
        float v2 = ep[(size_t)(t + 2) * 768];
        float v3 = ep[(size_t)(t + 3) * 768];
        seg[ids[t + 0]][tid] += v0;   // per-thread column: no races
        seg[ids[t + 1]][tid] += v1;
        seg[ids[t + 2]][tid] += v2;
        seg[ids[t + 3]][tid] += v3;
    }
    __syncthreads();

    for (int s = 0; s < 64; ++s) {
        float c = (float)cnt[s];
        float v = (c > 0.0f) ? (seg[s][tid] / c) : 0.0f;
        size_t o = ((size_t)b * 64 + s) * 768 + d0 + tid;
        unsigned short hi = f2bf(v);
        Ahi[o] = hi;
        Alo[o] = f2bf(v - bf2f(hi));
    }
}

// ---------------------------------------------------------------------------
// Kernel 2: f32 -> bf16 hi/lo split (weights)
// ---------------------------------------------------------------------------
__global__ void split_bf16(const float* __restrict__ src,
                           unsigned short* __restrict__ hi,
                           unsigned short* __restrict__ lo, int n)
{
    int i = blockIdx.x * 256 + threadIdx.x;
    if (i < n) {
        float v = src[i];
        unsigned short h = f2bf(v);
        hi[i] = h;
        lo[i] = f2bf(v - bf2f(h));
    }
}

// ---------------------------------------------------------------------------
// Kernel 3: w_hh (2,768,256) -> wP[dir][k/4][g][k%4] (coalesced float4 per g)
// ---------------------------------------------------------------------------
__global__ void whh_prep(const float* __restrict__ whh, float* __restrict__ wP)
{
    int i = blockIdx.x * 256 + threadIdx.x;
    if (i < 2 * 768 * 256) {
        int dir = i / (768 * 256);
        int rem = i % (768 * 256);
        int g = rem / 256, k = rem % 256;
        wP[(((size_t)dir * 64 + (k >> 2)) * 768 + g) * 4 + (k & 3)] = whh[i];
    }
}

// ---------------------------------------------------------------------------
// Kernel 4: MFMA GEMM, C[m,n] = sum_k A[m,k]*W[n,k] + bias[n]  (B^T form).
// SPLIT=1: A,W given as bf16 (hi,lo); 3-term product ~ f32 accuracy.
// 128x128 tile, BK=32, 4 waves (2x2 of 64x64), m97 2-barrier structure.
// ---------------------------------------------------------------------------
template <int SPLIT>
__global__ __launch_bounds__(256) void gemm_bt(
    const unsigned short* __restrict__ Ahi, const unsigned short* __restrict__ Alo,
    const unsigned short* __restrict__ Whi, const unsigned short* __restrict__ Wlo,
    float* __restrict__ C, int M, int N, int K,
    const float* __restrict__ bias, int do_relu)
{
    __shared__ unsigned short lds[4][128 * 32];   // [Ahi, Alo, Whi, Wlo]
    const int tid  = threadIdx.x;
    const int bM   = blockIdx.y * 128;
    const int bN   = blockIdx.x * 128;
    const int wid  = tid >> 6;
    const int lane = tid & 63;
    const int wr = wid >> 1, wc = wid & 1;
    const int fr = lane & 15, fq = lane >> 4;

    // staging: thread covers chunk tid (+256); chunk c -> row c/4, 8-elem seg c%4
    const int srow = tid >> 2;
    const int scol = (tid & 3) * 8;
    const unsigned short* a0 = Ahi + (size_t)(bM + srow) * K + scol;
    const unsigned short* a1 = Ahi + (size_t)(bM + 64 + srow) * K + scol;
    const unsigned short* w0 = Whi + (size_t)(bN + srow) * K + scol;
    const unsigned short* w1 = Whi + (size_t)(bN + 64 + srow) * K + scol;
    const unsigned short *al0 = nullptr, *al1 = nullptr, *wl0 = nullptr, *wl1 = nullptr;
    if constexpr (SPLIT) {
        al0 = Alo + (size_t)(bM + srow) * K + scol;
        al1 = Alo + (size_t)(bM + 64 + srow) * K + scol;
        wl0 = Wlo + (size_t)(bN + srow) * K + scol;
        wl1 = Wlo + (size_t)(bN + 64 + srow) * K + scol;
    }
    const unsigned int lb0 = (unsigned)(wid * 64) * 16;         // wave-uniform LDS byte base
    const unsigned int lb1 = (unsigned)(256 + wid * 64) * 16;

    f32x4 acc[4][4] = {};

    for (int k0 = 0; k0 < K; k0 += 32) {
        __syncthreads();
        GLL16(a0 + k0, (char*)&lds[0][0] + lb0);
        GLL16(a1 + k0, (char*)&lds[0][0] + lb1);
        GLL16(w0 + k0, (char*)&lds[2][0] + lb0);
        GLL16(w1 + k0, (char*)&lds[2][0] + lb1);
        if constexpr (SPLIT) {
            GLL16(al0 + k0, (char*)&lds[1][0] + lb0);
            GLL16(al1 + k0, (char*)&lds[1][0] + lb1);
            GLL16(wl0 + k0, (char*)&lds[3][0] + lb0);
            GLL16(wl1 + k0, (char*)&lds[3][0] + lb1);
        }
        __syncthreads();

        bf16x8 af[4], wf[4], alf[4], wlf[4];
#pragma unroll
        for (int m = 0; m < 4; ++m) {
            int r = wr * 64 + m * 16 + fr;
            af[m] = *(const bf16x8*)&lds[0][r * 32 + fq * 8];
            if constexpr (SPLIT) alf[m] = *(const bf16x8*)&lds[1][r * 32 + fq * 8];
        }
#pragma unroll
        for (int n = 0; n < 4; ++n) {
            int r = wc * 64 + n * 16 + fr;
            wf[n] = *(const bf16x8*)&lds[2][r * 32 + fq * 8];
            if constexpr (SPLIT) wlf[n] = *(const bf16x8*)&lds[3][r * 32 + fq * 8];
        }
#pragma unroll
        for (int m = 0; m < 4; ++m)
#pragma unroll
            for (int n = 0; n < 4; ++n) {
                acc[m][n] = __builtin_amdgcn_mfma_f32_16x16x32_bf16(af[m], wf[n], acc[m][n], 0, 0, 0);
                if constexpr (SPLIT) {
                    acc[m][n] = __builtin_amdgcn_mfma_f32_16x16x32_bf16(af[m], wlf[n], acc[m][n], 0, 0, 0);
                    acc[m][n] = __builtin_amdgcn_mfma_f32_16x16x32_bf16(alf[m], wf[n], acc[m][n], 0, 0, 0);
                }
            }
    }

    // epilogue: C/D layout col=lane&15, row=(lane>>4)*4+reg  [m89/m91 verified]
#pragma unroll
    for (int m = 0; m < 4; ++m)
#pragma unroll
        for (int j = 0; j < 4; ++j) {
            int grow = bM + wr * 64 + m * 16 + fq * 4 + j;
            float* crow = C + (size_t)grow * N;
#pragma unroll
            for (int n = 0; n < 4; ++n) {
                int gcol = bN + wc * 64 + n * 16 + fr;
                float v = acc[m][n][j] + bias[gcol];
                if (do_relu) v = fmaxf(v, 0.0f);
                crow[gcol] = v;
            }
        }
}

// ---------------------------------------------------------------------------
// Kernel 5: GRU recurrence, one direction+4 batches per block (no grid sync —
// recurrence is batch-parallel).  f32 throughout.  grid 256, block 256.
// Thread tid owns hidden unit j=tid: computes hr/hz/hn for its unit, then the
// full gate update locally (gate order r,z,n matches jnp.split thirds).
// ---------------------------------------------------------------------------
__global__ __launch_bounds__(256) void gru_rec(
    const float* __restrict__ gi,    // (B,64,1536)  [0:768)=fwd, [768:1536)=bwd
    const float* __restrict__ wP,    // [2][64][768][4] f32
    const float* __restrict__ bhh,   // (2,768)
    unsigned short* __restrict__ Hhi, unsigned short* __restrict__ Hlo) // (B,64,512)
{
    __shared__ __align__(16) float h[4][256];
    const int tid = threadIdx.x;
    const int dir = blockIdx.x >> 7;          // 128 blocks fwd, 128 bwd
    const int b0  = (blockIdx.x & 127) * 4;
    const float br = bhh[dir * 768 + tid];
    const float bz = bhh[dir * 768 + 256 + tid];
    const float bn = bhh[dir * 768 + 512 + tid];
    const float4* wp4 = ((const float4*)wP) + (size_t)dir * 64 * 768;

#pragma unroll
    for (int b = 0; b < 4; ++b) h[b][tid] = 0.0f;
    float hreg[4] = {0.f, 0.f, 0.f, 0.f};
    __syncthreads();

    for (int ti = 0; ti < 64; ++ti) {
        const int t = dir ? (63 - ti) : ti;
        float ar[4] = {}, az[4] = {}, an[4] = {};
#pragma unroll 4
        for (int k4 = 0; k4 < 64; ++k4) {
            const float4 w_r = wp4[k4 * 768 + tid];
            const float4 w_z = wp4[k4 * 768 + 256 + tid];
            const float4 w_n = wp4[k4 * 768 + 512 + tid];
#pragma unroll
            for (int b = 0; b < 4; ++b) {
                const float4 hb = *(const float4*)&h[b][k4 * 4];
                ar[b] = fmaf(hb.w, w_r.w, fmaf(hb.z, w_r.z, fmaf(hb.y, w_r.y, fmaf(hb.x, w_r.x, ar[b]))));
                az[b] = fmaf(hb.w, w_z.w, fmaf(hb.z, w_z.z, fmaf(hb.y, w_z.y, fmaf(hb.x, w_z.x, az[b]))));
                an[b] = fmaf(hb.w, w_n.w, fmaf(hb.z, w_n.z, fmaf(hb.y, w_n.y, fmaf(hb.x, w_n.x, an[b]))));
            }
        }
        float hnew[4];
#pragma unroll
        for (int b = 0; b < 4; ++b) {
            const size_t gib = ((size_t)(b0 + b) * 64 + t) * 1536 + dir * 768 + tid;
            const float gr = gi[gib], gz = gi[gib + 256], gn = gi[gib + 512];
            const float r = 1.0f / (1.0f + expf(-(gr + ar[b] + br)));
            const float z = 1.0f / (1.0f + expf(-(gz + az[b] + bz)));
            const float n = tanhf(gn + r * (an[b] + bn));
            hnew[b] = (1.0f - z) * n + z * hreg[b];
        }
        __syncthreads();   // all k4-loop reads of h done before overwrite
#pragma unroll
        for (int b = 0; b < 4; ++b) {
            h[b][tid] = hnew[b];
            hreg[b]   = hnew[b];
            const size_t ho = ((size_t)(b0 + b) * 64 + t) * 512 + dir * 256 + tid;
            unsigned short hi = f2bf(hnew[b]);
            Hhi[ho] = hi;
            Hlo[ho] = f2bf(hnew[b] - bf2f(hi));
        }
        __syncthreads();   // writes visible before next step's reads
    }
}

// ---------------------------------------------------------------------------
// Kernel 6: output head. logits[b,c,s] = feats[b,s,:] . out_w[c,:] + out_b[c]
// out layout (B,2,64). One block per b; one wave per 16 s-values.
// ---------------------------------------------------------------------------
__global__ __launch_bounds__(256) void out_head(
    const float* __restrict__ feats, const float* __restrict__ ow,
    const float* __restrict__ ob, float* __restrict__ out)
{
    const int b = blockIdx.x;
    const int wid = threadIdx.x >> 6, lane = threadIdx.x & 63;
    float w0[8], w1[8];
#pragma unroll
    for (int i = 0; i < 8; ++i) { w0[i] = ow[lane * 8 + i]; w1[i] = ow[512 + lane * 8 + i]; }
    const float bo0 = ob[0], bo1 = ob[1];
    for (int s = wid; s < 64; s += 4) {
        const float* f = feats + ((size_t)b * 64 + s) * 512 + lane * 8;
        float a0 = 0.f, a1 = 0.f;
#pragma unroll
        for (int i = 0; i < 8; ++i) { float v = f[i]; a0 = fmaf(v, w0[i], a0); a1 = fmaf(v, w1[i], a1); }
#pragma unroll
        for (int off = 32; off > 0; off >>= 1) { a0 += __shfl_down(a0, off); a1 += __shfl_down(a1, off); }
        if (lane == 0) {
            out[(size_t)b * 128 + s]      = a0 + bo0;
            out[(size_t)b * 128 + 64 + s] = a1 + bo1;
        }
    }
}

// ---------------------------------------------------------------------------
extern "C" void kernel_launch(void* const* d_in, const int* in_sizes, int n_in,
                              void* d_out, int out_size, void* d_ws, size_t ws_size,
                              hipStream_t stream)
{
    (void)in_sizes; (void)n_in; (void)out_size;
    const float* emb     = (const float*)d_in[0];
    const int*   wids    = (const int*)d_in[1];
    const float* w_ih_l0 = (const float*)d_in[2];
    const float* w_hh_l0 = (const float*)d_in[3];
    const float* b_ih_l0 = (const float*)d_in[4];
    const float* b_hh_l0 = (const float*)d_in[5];
    const float* w_ih_l1 = (const float*)d_in[6];
    const float* w_hh_l1 = (const float*)d_in[7];
    const float* b_ih_l1 = (const float*)d_in[8];
    const float* b_hh_l1 = (const float*)d_in[9];
    const float* ff_w    = (const float*)d_in[10];
    const float* ff_b    = (const float*)d_in[11];
    const float* out_w   = (const float*)d_in[12];
    const float* out_b   = (const float*)d_in[13];
    float* out = (float*)d_out;
    char* ws = (char*)d_ws;

    // ws layout (bytes); regions reused across the pipeline:
    //   [0,100663296)            A region: avg hi|lo -> later H0 hi|lo -> later H1 hi|lo
    //   [100663296, 301989888)   GI (201.3MB) -> later FEATS (67.1MB)
    //   [301989888, ...)         converted weights (~12.1 MB)
    const size_t AHI = 0, ALO = 50331648;
    const size_t H0HI = 0, H0LO = 33554432;
    const size_t H1HI = 0, H1LO = 33554432;
    const size_t GI = 100663296;
    const size_t FEATS = GI;
    const size_t WIH0H = 301989888, WIH0L = WIH0H + 2359296;
    const size_t WIH1H = WIH0L + 2359296, WIH1L = WIH1H + 1572864;
    const size_t WFFH  = WIH1L + 1572864, WFFL = WFFH + 524288;
    const size_t WP0   = WFFL + 524288, WP1 = WP0 + 1572864;
    const size_t WS_NEEDED = WP1 + 1572864;     // 314,048,512 B
    if (ws_size < WS_NEEDED) return;            // (would show up as pure-poison output)

    // 1) segment mean -> avg (bf16 hi/lo)
    seg_mean<<<dim3(512, 3), 256, 0, stream>>>(emb, wids,
        (unsigned short*)(ws + AHI), (unsigned short*)(ws + ALO));

    // 2) weight conversions (every call; inputs restored each launch)
    split_bf16<<<(1179648 + 255) / 256, 256, 0, stream>>>(w_ih_l0,
        (unsigned short*)(ws + WIH0H), (unsigned short*)(ws + WIH0L), 1179648);
    split_bf16<<<(786432 + 255) / 256, 256, 0, stream>>>(w_ih_l1,
        (unsigned short*)(ws + WIH1H), (unsigned short*)(ws + WIH1L), 786432);
    split_bf16<<<(262144 + 255) / 256, 256, 0, stream>>>(ff_w,
        (unsigned short*)(ws + WFFH), (unsigned short*)(ws + WFFL), 262144);
    whh_prep<<<(393216 + 255) / 256, 256, 0, stream>>>(w_hh_l0, (float*)(ws + WP0));
    whh_prep<<<(393216 + 255) / 256, 256, 0, stream>>>(w_hh_l1, (float*)(ws + WP1));

    // 3) gi = avg @ w_ih_l0^T + b_ih_l0   (M=32768, N=1536, K=768, split-bf16)
    gemm_bt<1><<<dim3(12, 256), 256, 0, stream>>>(
        (const unsigned short*)(ws + AHI), (const unsigned short*)(ws + ALO),
        (const unsigned short*)(ws + WIH0H), (const unsigned short*)(ws + WIH0L),
        (float*)(ws + GI), 32768, 1536, 768, b_ih_l0, 0);

    // 4) GRU layer 0 scan -> H0 (bf16 hi/lo)
    gru_rec<<<256, 256, 0, stream>>>((const float*)(ws + GI), (const float*)(ws + WP0),
        b_hh_l0, (unsigned short*)(ws + H0HI), (unsigned short*)(ws + H0LO));

    // 5) gi = H0 @ w_ih_l1^T + b_ih_l1   (K=512)
    gemm_bt<1><<<dim3(12, 256), 256, 0, stream>>>(
        (const unsigned short*)(ws + H0HI), (const unsigned short*)(ws + H0LO),
        (const unsigned short*)(ws + WIH1H), (const unsigned short*)(ws + WIH1L),
        (float*)(ws + GI), 32768, 1536, 512, b_ih_l1, 0);

    // 6) GRU layer 1 scan -> H1
    gru_rec<<<256, 256, 0, stream>>>((const float*)(ws + GI), (const float*)(ws + WP1),
        b_hh_l1, (unsigned short*)(ws + H1HI), (unsigned short*)(ws + H1LO));

    // 7) feats = relu(H1 @ ff_w^T + ff_b)   (plain bf16: no cascading error)
    gemm_bt<0><<<dim3(4, 256), 256, 0, stream>>>(
        (const unsigned short*)(ws + H1HI), nullptr,
        (const unsigned short*)(ws + WFFH), nullptr,
        (float*)(ws + FEATS), 32768, 512, 512, ff_b, 1);

    // 8) logits + transpose -> (B,2,64)
    out_head<<<512, 256, 0, stream>>>((const float*)(ws + FEATS), out_w, out_b, out);
}